// Round 1
// baseline (438.765 us; speedup 1.0000x reference)
//
#include <hip/hip_runtime.h>
#include <stdint.h>

#define N_PTS 200000
#define SITES 131072          // B * 32^3
#define CINC  128
#define COUTC 256
#define KTOT  1024            // 8 subvoxels * 128 cin
#define LEAK  0.333f
#define EPSbn 1e-4f

typedef __attribute__((ext_vector_type(8))) short bf16x8;
typedef __attribute__((ext_vector_type(4))) float f32x4;

// ---- helpers -------------------------------------------------------------

__device__ __forceinline__ unsigned short f2bf(float f) {
  union { float f; unsigned u; } un; un.f = f;
  unsigned u = un.u;
  u += 0x7fffu + ((u >> 16) & 1u);   // RNE
  return (unsigned short)(u >> 16);
}

__device__ __forceinline__ void gload_lds16(const void* g, void* l) {
  __builtin_amdgcn_global_load_lds(
      (__attribute__((address_space(1))) void*)(g),
      (__attribute__((address_space(3))) void*)(l), 16, 0, 0);
}

// ---- W^T convert: WT[cout][k] = W[k/128 (sub)][k%128 (cin)][cout], bf16 ---

__global__ void wcvt_k(const float* __restrict__ W, unsigned short* __restrict__ WT) {
  int i = blockIdx.x * 256 + threadIdx.x;      // 262144 total
  int cout = i >> 10, k = i & 1023;
  WT[i] = f2bf(W[k * COUTC + cout]);
}

// ---- scatter points into bf16 blocked grid -------------------------------

__global__ void scatter_k(const float* __restrict__ feat, const int* __restrict__ coords,
                          const int* __restrict__ bidx, unsigned short* __restrict__ grid,
                          unsigned char* __restrict__ occ) {
  int p = blockIdx.x * 4 + (threadIdx.x >> 6);   // one wave per point
  int l = threadIdx.x & 63;
  if (p >= N_PTS) return;
  int b = bidx[p];
  int x = coords[p * 3 + 0], y = coords[p * 3 + 1], z = coords[p * 3 + 2];
  int osite = b * 32768 + (((x >> 1) * 32 + (y >> 1)) << 5) + (z >> 1);
  int sub = ((x & 1) << 2) | ((y & 1) << 1) | (z & 1);
  if (l == 0) occ[osite] = 1;
  float2 v = reinterpret_cast<const float2*>(feat)[p * 64 + l];
  unsigned pk = ((unsigned)f2bf(v.y) << 16) | (unsigned)f2bf(v.x);
  unsigned short* dst = grid + (((size_t)osite * 8 + sub) << 7) + (l << 1);
  asm volatile("global_atomic_pk_add_bf16 %0, %1, off"
               :: "v"((unsigned long long)(uintptr_t)dst), "v"(pk) : "memory");
}

// ---- GEMM: out[site][cout] = grid[site][0:1024] . WT[cout][0:1024] -------
// BM=128, BN=256, BK=64, 8 waves (2x4), 16x16x32 bf16 MFMA.
// LDS linear dest for global_load_lds; XOR-swizzle (16B chunk ^ row&7)
// applied on the GLOBAL source and again on ds_read (rule 21).

__global__ __launch_bounds__(512, 1) void conv_k(
    const unsigned short* __restrict__ gridA, const unsigned short* __restrict__ WT,
    const unsigned char* __restrict__ occ, const float* __restrict__ bias,
    float* __restrict__ out, float* __restrict__ gsum, float* __restrict__ gsumsq) {
  __shared__ __align__(16) char lds[49152];
  char* Alds = lds;              // [128][64] bf16 = 16 KB (swizzled)
  char* Blds = lds + 16384;      // [256][64] bf16 = 32 KB (swizzled)

  const int tid = threadIdx.x;
  const int lane = tid & 63;
  const int wid = tid >> 6;
  const int wm = wid >> 2, wn = wid & 3;
  const int mt = blockIdx.x;

  const char* Ab = (const char*)(gridA + (size_t)mt * 128 * KTOT);
  const char* Bb = (const char*)WT;

  f32x4 acc[4][4];
#pragma unroll
  for (int m = 0; m < 4; ++m)
#pragma unroll
    for (int n = 0; n < 4; ++n) acc[m][n] = (f32x4){0.f, 0.f, 0.f, 0.f};

  for (int t = 0; t < 16; ++t) {
    // stage A: 1024 16B slots, 2 per thread
#pragma unroll
    for (int i = 0; i < 2; ++i) {
      int s = tid + i * 512;
      int row = s >> 3, c = s & 7;
      gload_lds16(Ab + row * 2048 + t * 128 + ((c ^ (row & 7)) << 4),
                  Alds + (s << 4));
    }
    // stage B: 2048 slots, 4 per thread
#pragma unroll
    for (int i = 0; i < 4; ++i) {
      int s = tid + i * 512;
      int row = s >> 3, c = s & 7;
      gload_lds16(Bb + row * 2048 + t * 128 + ((c ^ (row & 7)) << 4),
                  Blds + (s << 4));
    }
    __syncthreads();   // compiler drains vmcnt before barrier
#pragma unroll
    for (int ks = 0; ks < 2; ++ks) {
      bf16x8 af[4], bfr[4];
#pragma unroll
      for (int m = 0; m < 4; ++m) {
        int row = wm * 64 + m * 16 + (lane & 15);
        int bc = ((ks * 4 + (lane >> 4)) ^ (row & 7)) << 4;
        af[m] = *(const bf16x8*)(Alds + row * 128 + bc);
      }
#pragma unroll
      for (int n = 0; n < 4; ++n) {
        int row = wn * 64 + n * 16 + (lane & 15);
        int bc = ((ks * 4 + (lane >> 4)) ^ (row & 7)) << 4;
        bfr[n] = *(const bf16x8*)(Blds + row * 128 + bc);
      }
#pragma unroll
      for (int m = 0; m < 4; ++m)
#pragma unroll
        for (int n = 0; n < 4; ++n)
          acc[m][n] = __builtin_amdgcn_mfma_f32_16x16x32_bf16(af[m], bfr[n], acc[m][n], 0, 0, 0);
    }
    __syncthreads();
  }

  // epilogue: +bias, mask by site occupancy, write pre-BN out, partial stats
  const int colb = wn * 64 + (lane & 15);
  const int rowb = wm * 64 + ((lane >> 4) << 2);
  float msk[16];
#pragma unroll
  for (int m = 0; m < 4; ++m)
#pragma unroll
    for (int j = 0; j < 4; ++j) {
      int site = mt * 128 + rowb + m * 16 + j;
      msk[m * 4 + j] = occ[site] ? 1.0f : 0.0f;
    }
  float s[4] = {0.f, 0.f, 0.f, 0.f}, ss[4] = {0.f, 0.f, 0.f, 0.f};
#pragma unroll
  for (int n = 0; n < 4; ++n) {
    int cout = colb + n * 16;
    float bv = bias[cout];
#pragma unroll
    for (int m = 0; m < 4; ++m)
#pragma unroll
      for (int j = 0; j < 4; ++j) {
        int site = mt * 128 + rowb + m * 16 + j;
        float v = (acc[m][n][j] + bv) * msk[m * 4 + j];
        out[(size_t)site * COUTC + cout] = v;
        s[n] += v; ss[n] += v * v;
      }
  }
#pragma unroll
  for (int n = 0; n < 4; ++n) {
    float a = s[n], b = ss[n];
    a += __shfl_xor(a, 16); a += __shfl_xor(a, 32);
    b += __shfl_xor(b, 16); b += __shfl_xor(b, 32);
    if (lane < 16) {
      atomicAdd(&gsum[colb + n * 16], a);
      atomicAdd(&gsumsq[colb + n * 16], b);
    }
  }
}

// ---- stats: cnt = sum(occ); scale/shift per channel ----------------------

__global__ void stats_k(const unsigned char* __restrict__ occ,
                        const float* __restrict__ gsum, const float* __restrict__ gsumsq,
                        const float* __restrict__ gamma, const float* __restrict__ beta,
                        float* __restrict__ scsh) {
  __shared__ float red[4];
  int tid = threadIdx.x;   // 256
  const uint4* o4 = (const uint4*)occ;
  unsigned c = 0;
  for (int i = tid; i < SITES / 16; i += 256) {
    uint4 u = o4[i];
    c += __popc(u.x & 0x01010101u) + __popc(u.y & 0x01010101u)
       + __popc(u.z & 0x01010101u) + __popc(u.w & 0x01010101u);
  }
  float cf = (float)c;
  for (int off = 32; off > 0; off >>= 1) cf += __shfl_down(cf, off);
  if ((tid & 63) == 0) red[tid >> 6] = cf;
  __syncthreads();
  float cnt = red[0] + red[1] + red[2] + red[3];
  float mean = gsum[tid] / cnt;
  float var = gsumsq[tid] / cnt - mean * mean;
  float sc = rsqrtf(var + EPSbn) * gamma[tid];
  scsh[tid] = sc;
  scsh[256 + tid] = beta[tid] - mean * sc;
}

// ---- BN + LeakyReLU + mask, in place on d_out ----------------------------

__global__ void bn_k(float* __restrict__ out, const unsigned char* __restrict__ occ,
                     const float* __restrict__ scsh) {
  const int total = SITES * 64;   // float4 count
  int stride = gridDim.x * blockDim.x;
  for (int i = blockIdx.x * blockDim.x + threadIdx.x; i < total; i += stride) {
    float4 v = reinterpret_cast<float4*>(out)[i];
    float4 r;
    if (occ[i >> 6]) {
      int c4 = (i & 63) << 2;
      float s0 = scsh[c4], s1 = scsh[c4 + 1], s2 = scsh[c4 + 2], s3 = scsh[c4 + 3];
      float h0 = scsh[256 + c4], h1 = scsh[257 + c4], h2 = scsh[258 + c4], h3 = scsh[259 + c4];
      r.x = fmaf(v.x, s0, h0); if (r.x < 0.f) r.x *= LEAK;
      r.y = fmaf(v.y, s1, h1); if (r.y < 0.f) r.y *= LEAK;
      r.z = fmaf(v.z, s2, h2); if (r.z < 0.f) r.z *= LEAK;
      r.w = fmaf(v.w, s3, h3); if (r.w < 0.f) r.w *= LEAK;
    } else {
      r.x = r.y = r.z = r.w = 0.f;
    }
    reinterpret_cast<float4*>(out)[i] = r;
  }
}

// ---- launch --------------------------------------------------------------

extern "C" void kernel_launch(void* const* d_in, const int* in_sizes, int n_in,
                              void* d_out, int out_size, void* d_ws, size_t ws_size,
                              hipStream_t stream) {
  const float* feat   = (const float*)d_in[0];
  const int*   coords = (const int*)d_in[1];
  const int*   bidx   = (const int*)d_in[2];
  const float* W      = (const float*)d_in[3];
  const float* bias   = (const float*)d_in[4];
  const float* gamma  = (const float*)d_in[5];
  const float* beta   = (const float*)d_in[6];
  float* out = (float*)d_out;

  char* ws = (char*)d_ws;
  // layout: grid bf16 [131072][1024] | WT bf16 [256][1024] | occ u8 [131072] | stats f32
  unsigned short* grid = (unsigned short*)ws;                      // 268435456 B
  unsigned short* WT   = (unsigned short*)(ws + 268435456);        // 524288 B
  unsigned char*  occ  = (unsigned char*)(ws + 268959744);         // 131072 B
  float*          st   = (float*)(ws + 269090816);                 // gsum|gsumsq|scale|shift

  hipMemsetAsync(grid, 0, 268435456, stream);
  hipMemsetAsync(ws + 268959744, 0, 131072 + 2048, stream);        // occ + gsum + gsumsq

  wcvt_k   <<<1024,  256, 0, stream>>>(W, WT);
  scatter_k<<<50000, 256, 0, stream>>>(feat, coords, bidx, grid, occ);
  conv_k   <<<1024,  512, 0, stream>>>(grid, WT, occ, bias, out, st, st + 256);
  stats_k  <<<1,     256, 0, stream>>>(occ, st, st + 256, gamma, beta, st + 512);
  bn_k     <<<2048,  256, 0, stream>>>(out, occ, st + 512);
}